// Round 1
// baseline (853.325 us; speedup 1.0000x reference)
//
#include <hip/hip_runtime.h>
#include <hip/hip_bf16.h>
#include <math.h>

#define B_ 4
#define S_ 512
#define D_ 1024
#define H_ 16
#define HD_ 64
#define MCK 8
#define MS (B_*S_)                       // 2048
static const size_t BHS  = (size_t)B_*H_*S_;      // 32768
static const size_t BHSS = (size_t)B_*H_*S_*S_;   // 16777216

__device__ __forceinline__ float wave_max(float v){
#pragma unroll
  for(int o=32;o;o>>=1) v = fmaxf(v, __shfl_xor(v,o));
  return v;
}
__device__ __forceinline__ float wave_sum(float v){
#pragma unroll
  for(int o=32;o;o>>=1) v += __shfl_xor(v,o);
  return v;
}

// O1 = A1 @ W^T + bias; raw2 = (A2^2) @ (W^2)^T
// MODE 0: O2 = (sqrt(raw2)+1e-6)^2   (projection variance round-trip)
// MODE 1: O2 = sqrt(raw2)            (final out_scale)
template<int MODE>
__global__ __launch_bounds__(256) void dual_gemm(
    const float* __restrict__ A1, const float* __restrict__ A2,
    const float* __restrict__ W, const float* __restrict__ bias,
    float* __restrict__ O1, float* __restrict__ O2, int M, int N, int K)
{
  __shared__ float As1[32][68];
  __shared__ float As2[32][68];
  __shared__ float Ws[32][68];
  const int t = threadIdx.x;
  const int tx = t & 15, ty = t >> 4;
  const int m0 = blockIdx.y * 64, n0 = blockIdx.x * 64;
  float acc1[4][4] = {{0.f}}, acc2[4][4] = {{0.f}};
  for (int k0 = 0; k0 < K; k0 += 32) {
#pragma unroll
    for (int l = 0; l < 2; ++l) {
      int f = t + l*256;
      int row = f >> 3;
      int c0 = (f & 7) << 2;
      float4 a1 = *(const float4*)(A1 + (size_t)(m0+row)*K + k0 + c0);
      float4 a2 = *(const float4*)(A2 + (size_t)(m0+row)*K + k0 + c0);
      float4 w  = *(const float4*)(W  + (size_t)(n0+row)*K + k0 + c0);
      As1[c0+0][row]=a1.x; As1[c0+1][row]=a1.y; As1[c0+2][row]=a1.z; As1[c0+3][row]=a1.w;
      As2[c0+0][row]=a2.x*a2.x; As2[c0+1][row]=a2.y*a2.y; As2[c0+2][row]=a2.z*a2.z; As2[c0+3][row]=a2.w*a2.w;
      Ws [c0+0][row]=w.x;  Ws [c0+1][row]=w.y;  Ws [c0+2][row]=w.z;  Ws [c0+3][row]=w.w;
    }
    __syncthreads();
#pragma unroll
    for (int kk = 0; kk < 32; ++kk) {
      float a1v[4], a2v[4], wv[4], w2[4];
      *(float4*)a1v = *(const float4*)&As1[kk][ty*4];
      *(float4*)a2v = *(const float4*)&As2[kk][ty*4];
      *(float4*)wv  = *(const float4*)&Ws [kk][tx*4];
#pragma unroll
      for (int j=0;j<4;++j) w2[j] = wv[j]*wv[j];
#pragma unroll
      for (int i=0;i<4;++i)
#pragma unroll
        for (int j=0;j<4;++j) {
          acc1[i][j] += a1v[i]*wv[j];
          acc2[i][j] += a2v[i]*w2[j];
        }
    }
    __syncthreads();
  }
#pragma unroll
  for (int i=0;i<4;++i) {
    int m = m0 + ty*4 + i;
#pragma unroll
    for (int j=0;j<4;++j) {
      int n = n0 + tx*4 + j;
      float mu = acc1[i][j] + bias[n];
      float va = acc2[i][j];
      float o2;
      if (MODE==0) { float sc = sqrtf(va) + 1e-6f; o2 = sc*sc; }
      else         { o2 = sqrtf(va); }
      O1[(size_t)m*N + n] = mu;
      O2[(size_t)m*N + n] = o2;
    }
  }
}

// l_mu/l_var over [B,H,S,S]; per-block 64x64 (q,k) tile for one (b,h)
__global__ __launch_bounds__(256) void score_kernel(
    const float* __restrict__ qm_, const float* __restrict__ qv_,
    const float* __restrict__ km_, const float* __restrict__ kv_,
    float* __restrict__ lmu, float* __restrict__ lvar,
    const float* __restrict__ tau_p)
{
  __shared__ float Qm[32][68], Qv[32][68], Km[32][68], Kv[32][68];
  const int t = threadIdx.x;
  const int tx = t & 15, ty = t >> 4;
  const int k0 = blockIdx.x * 64, q0 = blockIdx.y * 64;
  const int bh = blockIdx.z;
  const int b = bh >> 4, h = bh & 15;
  const float* qmB = qm_ + ((size_t)b*S_)*D_ + h*HD_;
  const float* qvB = qv_ + ((size_t)b*S_)*D_ + h*HD_;
  const float* kmB = km_ + ((size_t)b*S_)*D_ + h*HD_;
  const float* kvB = kv_ + ((size_t)b*S_)*D_ + h*HD_;
  float mu[4][4]={{0.f}}, va[4][4]={{0.f}};
  for (int d0 = 0; d0 < HD_; d0 += 32) {
#pragma unroll
    for (int l = 0; l < 2; ++l) {
      int f = t + l*256;
      int row = f >> 3;
      int c0 = (f & 7) << 2;
      float4 v;
      v = *(const float4*)(qmB + (size_t)(q0+row)*D_ + d0 + c0);
      Qm[c0+0][row]=v.x; Qm[c0+1][row]=v.y; Qm[c0+2][row]=v.z; Qm[c0+3][row]=v.w;
      v = *(const float4*)(qvB + (size_t)(q0+row)*D_ + d0 + c0);
      Qv[c0+0][row]=v.x; Qv[c0+1][row]=v.y; Qv[c0+2][row]=v.z; Qv[c0+3][row]=v.w;
      v = *(const float4*)(kmB + (size_t)(k0+row)*D_ + d0 + c0);
      Km[c0+0][row]=v.x; Km[c0+1][row]=v.y; Km[c0+2][row]=v.z; Km[c0+3][row]=v.w;
      v = *(const float4*)(kvB + (size_t)(k0+row)*D_ + d0 + c0);
      Kv[c0+0][row]=v.x; Kv[c0+1][row]=v.y; Kv[c0+2][row]=v.z; Kv[c0+3][row]=v.w;
    }
    __syncthreads();
#pragma unroll
    for (int kk = 0; kk < 32; ++kk) {
      float qmv[4], qvv[4], kmv[4], kvv[4], qm2[4], kb[4];
      *(float4*)qmv = *(const float4*)&Qm[kk][ty*4];
      *(float4*)qvv = *(const float4*)&Qv[kk][ty*4];
      *(float4*)kmv = *(const float4*)&Km[kk][tx*4];
      *(float4*)kvv = *(const float4*)&Kv[kk][tx*4];
#pragma unroll
      for (int i=0;i<4;++i) qm2[i] = qmv[i]*qmv[i];
#pragma unroll
      for (int j=0;j<4;++j) kb[j] = kmv[j]*kmv[j] + kvv[j];
#pragma unroll
      for (int i=0;i<4;++i)
#pragma unroll
        for (int j=0;j<4;++j) {
          mu[i][j] += qmv[i]*kmv[j];
          va[i][j] += qm2[i]*kvv[j];
          va[i][j] += qvv[i]*kb[j];
        }
    }
    __syncthreads();
  }
  const float tau = *tau_p;
  const float itau = 1.0f / tau;
#pragma unroll
  for (int i=0;i<4;++i) {
    int q = q0 + ty*4 + i;
#pragma unroll
    for (int j=0;j<4;++j) {
      int k = k0 + tx*4 + j;
      size_t off = ((size_t)bh*S_ + q)*S_ + k;
      float l_mu = (mu[i][j] * 0.125f) * itau;
      float l_va = ((va[i][j] + 1e-6f) * (1.0f/64.0f) + 1e-6f) * (itau*itau) + 1e-6f;
      lmu[off]  = l_mu;
      lvar[off] = l_va;
    }
  }
}

// one wave per query row: top-8, MC softmax mean, rest softmax, combine.
// NOTE: attn may alias lmu (each wave reads its row fully before writing).
__global__ __launch_bounds__(256) void attn_kernel(
    const float* lmu, const float* __restrict__ lvar,
    const float* __restrict__ eps, float* attn)
{
  const int wid  = threadIdx.x >> 6;
  const int lane = threadIdx.x & 63;
  const size_t r = (size_t)blockIdx.x * 4 + wid;     // 0..32767
  const float* mrow = lmu  + r*S_;
  const float* vrow = lvar + r*S_;
  float mu[8], va[8], sd[8];
#pragma unroll
  for (int i=0;i<8;++i) {
    mu[i] = mrow[lane + 64*i];
    va[i] = vrow[lane + 64*i];
    sd[i] = sqrtf(fmaxf(va[i], 1e-9f));
  }
  // ---- top-8 by l_mu (tie-break: lowest index, matching lax.top_k) ----
  unsigned sel = 0;
  float x[8];
#pragma unroll
  for (int i=0;i<8;++i) x[i] = mu[i];
  for (int tsel=0; tsel<8; ++tsel) {
    float bv = -INFINITY; int bi = 0x7fffffff;
#pragma unroll
    for (int i=0;i<8;++i) {
      int gi = lane + 64*i;
      if (x[i] > bv || (x[i] == bv && gi < bi)) { bv = x[i]; bi = gi; }
    }
    for (int o=32;o;o>>=1) {
      float ov = __shfl_xor(bv,o); int oi = __shfl_xor(bi,o);
      if (ov > bv || (ov == bv && oi < bi)) { bv = ov; bi = oi; }
    }
    if ((bi & 63) == lane) { sel |= 1u << (bi >> 6); x[bi >> 6] = -INFINITY; }
  }
  // ---- MC-sample softmax mean ----
  float pacc[8] = {0,0,0,0,0,0,0,0};
  for (int mc=0; mc<MCK; ++mc) {
    const float* ep = eps + (size_t)mc*BHSS + r*S_ + lane;
    float xv[8];
#pragma unroll
    for (int i=0;i<8;++i) xv[i] = mu[i] + sd[i]*ep[64*i];
    float m = -INFINITY;
#pragma unroll
    for (int i=0;i<8;++i) m = fmaxf(m, xv[i]);
    m = wave_max(m);
    float e[8], zs = 0.f;
#pragma unroll
    for (int i=0;i<8;++i) { e[i] = __expf(xv[i]-m); zs += e[i]; }
    zs = wave_sum(zs);
    float inv = 1.0f / zs;
#pragma unroll
    for (int i=0;i<8;++i) pacc[i] += e[i]*inv;
  }
  // ---- rest (logit-normal) softmax with top-k excluded ----
  float adj[8];
#pragma unroll
  for (int i=0;i<8;++i) {
    float a = mu[i] / sqrtf(1.0f + 0.39269908169872414f*va[i]);
    adj[i] = ((sel >> i) & 1u) ? -1e9f : a;
  }
  float m2 = -INFINITY;
#pragma unroll
  for (int i=0;i<8;++i) m2 = fmaxf(m2, adj[i]);
  m2 = wave_max(m2);
  float e2[8], z2 = 0.f;
#pragma unroll
  for (int i=0;i<8;++i) { e2[i] = __expf(adj[i]-m2); z2 += e2[i]; }
  z2 = wave_sum(z2);
  float inv2 = 1.0f / z2;
  // ---- combine ----
  float rest[8], tout[8], s = 0.f;
#pragma unroll
  for (int i=0;i<8;++i) {
    rest[i] = e2[i]*inv2;
    tout[i] = ((sel >> i) & 1u) ? pacc[i]*0.125f : rest[i];
    s += tout[i];
  }
  s = wave_sum(s);
  float rn = 1.0f / fmaxf(s, 1e-12f);
  float* arow = attn + r*S_;
#pragma unroll
  for (int i=0;i<8;++i) arow[lane + 64*i] = tout[i]*rn + rest[i];
}

// Y_mu = attn @ vm ; Y_var = attn^2 @ vv ; write y_loc / y_scale [B,S,D]
__global__ __launch_bounds__(256) void pv_kernel(
    const float* __restrict__ attn, const float* __restrict__ vm_,
    const float* __restrict__ vv_, float* __restrict__ y_loc, float* __restrict__ y_scale)
{
  __shared__ float At[32][68], Vm[32][68], Vv[32][68];
  const int t = threadIdx.x;
  const int tx = t & 15, ty = t >> 4;
  const int q0 = blockIdx.x * 64;
  const int bh = blockIdx.y;
  const int b = bh >> 4, h = bh & 15;
  const float* aB  = attn + (size_t)bh*S_*S_;
  const float* vmB = vm_ + ((size_t)b*S_)*D_ + h*HD_;
  const float* vvB = vv_ + ((size_t)b*S_)*D_ + h*HD_;
  float accm[4][4]={{0.f}}, accv[4][4]={{0.f}};
  for (int k0 = 0; k0 < S_; k0 += 32) {
#pragma unroll
    for (int l = 0; l < 2; ++l) {
      int f = t + l*256;
      int row = f >> 3, c0 = (f & 7) << 2;
      float4 a = *(const float4*)(aB + (size_t)(q0+row)*S_ + k0 + c0);
      At[c0+0][row]=a.x; At[c0+1][row]=a.y; At[c0+2][row]=a.z; At[c0+3][row]=a.w;
    }
#pragma unroll
    for (int l = 0; l < 2; ++l) {
      int f = t + l*256;
      int row = f >> 4, c0 = (f & 15) << 2;
      *(float4*)&Vm[row][c0] = *(const float4*)(vmB + (size_t)(k0+row)*D_ + c0);
      *(float4*)&Vv[row][c0] = *(const float4*)(vvB + (size_t)(k0+row)*D_ + c0);
    }
    __syncthreads();
#pragma unroll
    for (int kk = 0; kk < 32; ++kk) {
      float av[4], vmv[4], vvv[4];
      *(float4*)av  = *(const float4*)&At[kk][ty*4];
      *(float4*)vmv = *(const float4*)&Vm[kk][tx*4];
      *(float4*)vvv = *(const float4*)&Vv[kk][tx*4];
#pragma unroll
      for (int i=0;i<4;++i) {
        float a2 = av[i]*av[i];
#pragma unroll
        for (int j=0;j<4;++j) {
          accm[i][j] += av[i]*vmv[j];
          accv[i][j] += a2*vvv[j];
        }
      }
    }
    __syncthreads();
  }
#pragma unroll
  for (int i=0;i<4;++i) {
    int q = q0 + ty*4 + i;
#pragma unroll
    for (int j=0;j<4;++j) {
      int d = tx*4 + j;
      size_t off = ((size_t)b*S_ + q)*D_ + h*HD_ + d;
      y_loc[off]   = accm[i][j];
      y_scale[off] = sqrtf(accv[i][j] + 1e-6f) + 1e-6f;
    }
  }
}

extern "C" void kernel_launch(void* const* d_in, const int* in_sizes, int n_in,
                              void* d_out, int out_size, void* d_ws, size_t ws_size,
                              hipStream_t stream)
{
  const float* Qloc = (const float*)d_in[0];
  const float* Qsc  = (const float*)d_in[1];
  const float* Kloc = (const float*)d_in[2];
  const float* Ksc  = (const float*)d_in[3];
  const float* Vloc = (const float*)d_in[4];
  const float* Vsc  = (const float*)d_in[5];
  const float* Wq = (const float*)d_in[6];  const float* bq = (const float*)d_in[7];
  const float* Wk = (const float*)d_in[8];  const float* bk = (const float*)d_in[9];
  const float* Wv = (const float*)d_in[10]; const float* bv = (const float*)d_in[11];
  const float* Wo = (const float*)d_in[12]; const float* bo = (const float*)d_in[13];
  const float* tau = (const float*)d_in[14];
  const float* eps = (const float*)d_in[15];

  float* ws = (float*)d_ws;
  const size_t P = (size_t)MS * D_;   // 2,097,152 floats
  float* q_mu = ws + 0*P;  float* q_v = ws + 1*P;
  float* k_mu = ws + 2*P;  float* k_v = ws + 3*P;
  float* v_mu = ws + 4*P;  float* v_v = ws + 5*P;
  float* lmu  = ws + 6*P;            // 8P floats [B,H,S,S]; attn aliases this
  float* lvar = ws + 14*P;           // 8P floats
  float* y_loc = ws + 14*P;          // aliases lvar (dead by the time pv writes)
  float* y_sc  = ws + 15*P;
  float* out_loc = (float*)d_out;
  float* out_sc  = out_loc + P;

  dim3 blk(256);
  dim3 gA(16, 32);                   // N/64, M/64
  dual_gemm<0><<<gA, blk, 0, stream>>>(Qloc, Qsc, Wq, bq, q_mu, q_v, MS, D_, D_);
  dual_gemm<0><<<gA, blk, 0, stream>>>(Kloc, Ksc, Wk, bk, k_mu, k_v, MS, D_, D_);
  dual_gemm<0><<<gA, blk, 0, stream>>>(Vloc, Vsc, Wv, bv, v_mu, v_v, MS, D_, D_);
  score_kernel<<<dim3(8,8,64), blk, 0, stream>>>(q_mu, q_v, k_mu, k_v, lmu, lvar, tau);
  attn_kernel<<<dim3((unsigned)(BHS/4)), blk, 0, stream>>>(lmu, lvar, eps, lmu);
  pv_kernel<<<dim3(8,64), blk, 0, stream>>>(lmu, v_mu, v_v, y_loc, y_sc);
  dual_gemm<1><<<gA, blk, 0, stream>>>(y_loc, y_sc, Wo, bo, out_loc, out_sc, MS, D_, D_);
}

// Round 2
// 403.533 us; speedup vs baseline: 2.1146x; 2.1146x over previous
//
#include <hip/hip_runtime.h>
#include <math.h>

#define B_ 4
#define S_ 512
#define D_ 1024
#define H_ 16
#define MCK 8
#define MS 2048
#define BHSS_ ((size_t)16777216)   // B*H*S*S
#define BHS_  ((size_t)32768)

typedef __attribute__((ext_vector_type(8))) __bf16 bf16x8;
typedef __attribute__((ext_vector_type(4))) __bf16 bf16x4;
typedef __attribute__((ext_vector_type(4))) float f32x4;

__device__ __forceinline__ f32x4 mfma16(bf16x8 a, bf16x8 b, f32x4 c) {
  return __builtin_amdgcn_mfma_f32_16x16x32_bf16(a, b, c, 0, 0, 0);
}
__device__ __forceinline__ bf16x8 sq8(bf16x8 x) {
  bf16x8 r;
#pragma unroll
  for (int i = 0; i < 8; ++i) { float f = (float)x[i]; r[i] = (__bf16)(f * f); }
  return r;
}
__device__ __forceinline__ float wave_max(float v) {
#pragma unroll
  for (int o = 32; o; o >>= 1) v = fmaxf(v, __shfl_xor(v, o));
  return v;
}
__device__ __forceinline__ float wave_sum(float v) {
#pragma unroll
  for (int o = 32; o; o >>= 1) v += __shfl_xor(v, o);
  return v;
}

// ---------- input conversion: (loc,scale) -> (hi, lo, scale^2) bf16 ----------
__global__ __launch_bounds__(256) void conv_ls(
    const float* __restrict__ l0, const float* __restrict__ s0,
    const float* __restrict__ l1, const float* __restrict__ s1,
    const float* __restrict__ l2, const float* __restrict__ s2,
    __bf16* h0, __bf16* o0, __bf16* v0,
    __bf16* h1, __bf16* o1, __bf16* v1,
    __bf16* h2, __bf16* o2, __bf16* v2)
{
  const int tn = blockIdx.x >> 10;
  const size_t i0 = ((size_t)(blockIdx.x & 1023) * 256 + threadIdx.x) * 8;
  const float* L = tn == 0 ? l0 : tn == 1 ? l1 : l2;
  const float* S = tn == 0 ? s0 : tn == 1 ? s1 : s2;
  __bf16* Hh = tn == 0 ? h0 : tn == 1 ? h1 : h2;
  __bf16* Lo = tn == 0 ? o0 : tn == 1 ? o1 : o2;
  __bf16* V2 = tn == 0 ? v0 : tn == 1 ? v1 : v2;
  float4 x0 = *(const float4*)(L + i0), x1 = *(const float4*)(L + i0 + 4);
  float4 y0 = *(const float4*)(S + i0), y1 = *(const float4*)(S + i0 + 4);
  float xs[8] = {x0.x, x0.y, x0.z, x0.w, x1.x, x1.y, x1.z, x1.w};
  float ys[8] = {y0.x, y0.y, y0.z, y0.w, y1.x, y1.y, y1.z, y1.w};
  bf16x8 hh, ll, vv;
#pragma unroll
  for (int i = 0; i < 8; ++i) {
    __bf16 h = (__bf16)xs[i];
    hh[i] = h;
    ll[i] = (__bf16)(xs[i] - (float)h);
    vv[i] = (__bf16)(ys[i] * ys[i]);
  }
  *(bf16x8*)(Hh + i0) = hh;
  *(bf16x8*)(Lo + i0) = ll;
  *(bf16x8*)(V2 + i0) = vv;
}

// ---------- weight conversion: W -> (hi, lo, W^2) bf16 ----------
__global__ __launch_bounds__(256) void conv_w(
    const float* __restrict__ w0, const float* __restrict__ w1,
    const float* __restrict__ w2, const float* __restrict__ w3,
    __bf16* h0, __bf16* o0, __bf16* q0,
    __bf16* h1, __bf16* o1, __bf16* q1,
    __bf16* h2, __bf16* o2, __bf16* q2,
    __bf16* h3, __bf16* o3, __bf16* q3)
{
  const int tn = blockIdx.x >> 9;
  const size_t i0 = ((size_t)(blockIdx.x & 511) * 256 + threadIdx.x) * 8;
  const float* W = tn == 0 ? w0 : tn == 1 ? w1 : tn == 2 ? w2 : w3;
  __bf16* Hh = tn == 0 ? h0 : tn == 1 ? h1 : tn == 2 ? h2 : h3;
  __bf16* Lo = tn == 0 ? o0 : tn == 1 ? o1 : tn == 2 ? o2 : o3;
  __bf16* Qq = tn == 0 ? q0 : tn == 1 ? q1 : tn == 2 ? q2 : q3;
  float4 x0 = *(const float4*)(W + i0), x1 = *(const float4*)(W + i0 + 4);
  float xs[8] = {x0.x, x0.y, x0.z, x0.w, x1.x, x1.y, x1.z, x1.w};
  bf16x8 hh, ll, qq;
#pragma unroll
  for (int i = 0; i < 8; ++i) {
    __bf16 h = (__bf16)xs[i];
    hh[i] = h;
    ll[i] = (__bf16)(xs[i] - (float)h);
    qq[i] = (__bf16)(xs[i] * xs[i]);
  }
  *(bf16x8*)(Hh + i0) = hh;
  *(bf16x8*)(Lo + i0) = ll;
  *(bf16x8*)(Qq + i0) = qq;
}

// ---------- dual GEMM: mu = (Ah+Al)@(Wh+Wl)^T + bias (split, 3 MFMA)
//            var = A2 @ W2^T (1 MFMA)
// EPI 0 (Q/K proj): write mu_hi, mu_lo, mu^2, (sqrt(var)+1e-6)^2   [M][1024] bf16
// EPI 1 (V proj):   write transposed vmT_hi, vmT_lo, vvT  [B][H][64][512] bf16
// EPI 2 (output):   write out_loc, out_scale f32
template<int EPI>
__global__ __launch_bounds__(256) void dgemm(
    const __bf16* __restrict__ Ah, const __bf16* __restrict__ Al, const __bf16* __restrict__ A2,
    const __bf16* __restrict__ Wh, const __bf16* __restrict__ Wl, const __bf16* __restrict__ W2,
    const float* __restrict__ bias,
    void* __restrict__ P0, void* __restrict__ P1, void* __restrict__ P2, void* __restrict__ P3)
{
  __shared__ __bf16 sA[3][64][32];
  __shared__ __bf16 sW[3][64][32];
  const int t = threadIdx.x;
  const int lane = t & 63, wid = t >> 6;
  const int wm = wid >> 1, wn = wid & 1;
  const int m0 = blockIdx.y * 64, n0 = blockIdx.x * 64;
  f32x4 accM[2][2] = {}; f32x4 accV[2][2] = {};
  const int crow = t >> 2, ccol = (t & 3) * 8;
  for (int k0 = 0; k0 < D_; k0 += 32) {
    size_t ga = (size_t)(m0 + crow) * D_ + k0 + ccol;
    size_t gw = (size_t)(n0 + crow) * D_ + k0 + ccol;
    bf16x8 va0 = *(const bf16x8*)(Ah + ga);
    bf16x8 va1 = *(const bf16x8*)(Al + ga);
    bf16x8 va2 = *(const bf16x8*)(A2 + ga);
    bf16x8 vw0 = *(const bf16x8*)(Wh + gw);
    bf16x8 vw1 = *(const bf16x8*)(Wl + gw);
    bf16x8 vw2 = *(const bf16x8*)(W2 + gw);
    __syncthreads();
    *(bf16x8*)&sA[0][crow][ccol] = va0;
    *(bf16x8*)&sA[1][crow][ccol] = va1;
    *(bf16x8*)&sA[2][crow][ccol] = va2;
    *(bf16x8*)&sW[0][crow][ccol] = vw0;
    *(bf16x8*)&sW[1][crow][ccol] = vw1;
    *(bf16x8*)&sW[2][crow][ccol] = vw2;
    __syncthreads();
    const int fr = lane & 15, kc = (lane >> 4) * 8;
    bf16x8 fah[2], fal[2], fa2[2];
#pragma unroll
    for (int i = 0; i < 2; ++i) {
      int r = wm * 32 + i * 16 + fr;
      fah[i] = *(const bf16x8*)&sA[0][r][kc];
      fal[i] = *(const bf16x8*)&sA[1][r][kc];
      fa2[i] = *(const bf16x8*)&sA[2][r][kc];
    }
#pragma unroll
    for (int j = 0; j < 2; ++j) {
      int r = wn * 32 + j * 16 + fr;
      bf16x8 fwh = *(const bf16x8*)&sW[0][r][kc];
      bf16x8 fwl = *(const bf16x8*)&sW[1][r][kc];
      bf16x8 fw2 = *(const bf16x8*)&sW[2][r][kc];
#pragma unroll
      for (int i = 0; i < 2; ++i) {
        accM[i][j] = mfma16(fah[i], fwh, accM[i][j]);
        accM[i][j] = mfma16(fah[i], fwl, accM[i][j]);
        accM[i][j] = mfma16(fal[i], fwh, accM[i][j]);
        accV[i][j] = mfma16(fa2[i], fw2, accV[i][j]);
      }
    }
  }
  const int fr = lane & 15, fq = lane >> 4;
#pragma unroll
  for (int i = 0; i < 2; ++i)
#pragma unroll
    for (int j = 0; j < 2; ++j) {
      const int col = n0 + wn * 32 + j * 16 + fr;
      const int row0 = m0 + wm * 32 + i * 16 + fq * 4;
      f32x4 m_ = accM[i][j], v_ = accV[i][j];
      const float bcol = bias[col];
      if (EPI == 0) {
#pragma unroll
        for (int r = 0; r < 4; ++r) {
          size_t off = (size_t)(row0 + r) * D_ + col;
          float mu = m_[r] + bcol;
          __bf16 h = (__bf16)mu;
          float s = sqrtf(v_[r]) + 1e-6f;
          ((__bf16*)P0)[off] = h;
          ((__bf16*)P1)[off] = (__bf16)(mu - (float)h);
          ((__bf16*)P2)[off] = (__bf16)(mu * mu);
          ((__bf16*)P3)[off] = (__bf16)(s * s);
        }
      } else if (EPI == 1) {
        const int b = row0 >> 9, ss0 = row0 & 511;
        const int hh = col >> 6, dd = col & 63;
        size_t base = ((size_t)(b * H_ + hh) * 64 + dd) * S_ + ss0;
        bf16x4 vh, vl, vq;
#pragma unroll
        for (int r = 0; r < 4; ++r) {
          float mu = m_[r] + bcol;
          __bf16 h = (__bf16)mu;
          vh[r] = h;
          vl[r] = (__bf16)(mu - (float)h);
          float s = sqrtf(v_[r]) + 1e-6f;
          vq[r] = (__bf16)(s * s);
        }
        *(bf16x4*)((__bf16*)P0 + base) = vh;
        *(bf16x4*)((__bf16*)P1 + base) = vl;
        *(bf16x4*)((__bf16*)P2 + base) = vq;
      } else {
#pragma unroll
        for (int r = 0; r < 4; ++r) {
          size_t off = (size_t)(row0 + r) * D_ + col;
          ((float*)P0)[off] = m_[r] + bcol;
          ((float*)P1)[off] = sqrtf(v_[r]);
        }
      }
    }
}

// ---------- score: l_mu (f32, split-precision) and l_var (bf16) ----------
__global__ __launch_bounds__(256) void score_mfma(
    const __bf16* __restrict__ qh, const __bf16* __restrict__ ql,
    const __bf16* __restrict__ q2, const __bf16* __restrict__ qv,
    const __bf16* __restrict__ kh, const __bf16* __restrict__ kl,
    const __bf16* __restrict__ k2, const __bf16* __restrict__ kv,
    float* __restrict__ lmu, __bf16* __restrict__ lvar,
    const float* __restrict__ taup)
{
  __shared__ __bf16 sQ[4][64][32];
  __shared__ __bf16 sK[4][64][32];
  const int t = threadIdx.x;
  const int lane = t & 63, wid = t >> 6;
  const int wm = wid >> 1, wn = wid & 1;
  const int kk0 = blockIdx.x * 64, q0 = blockIdx.y * 64, bh = blockIdx.z;
  const int b = bh >> 4, h = bh & 15;
  const size_t hb = ((size_t)b * S_) * D_ + (size_t)h * 64;
  f32x4 accM[2][2] = {}; f32x4 accV[2][2] = {};
  const int crow = t >> 2, ccol = (t & 3) * 8;
  for (int d0 = 0; d0 < 64; d0 += 32) {
    size_t gq = hb + (size_t)(q0 + crow) * D_ + d0 + ccol;
    size_t gk = hb + (size_t)(kk0 + crow) * D_ + d0 + ccol;
    bf16x8 a0 = *(const bf16x8*)(qh + gq);
    bf16x8 a1 = *(const bf16x8*)(ql + gq);
    bf16x8 a2 = *(const bf16x8*)(q2 + gq);
    bf16x8 a3 = *(const bf16x8*)(qv + gq);
    bf16x8 b0 = *(const bf16x8*)(kh + gk);
    bf16x8 b1 = *(const bf16x8*)(kl + gk);
    bf16x8 b2 = *(const bf16x8*)(k2 + gk);
    bf16x8 b3 = *(const bf16x8*)(kv + gk);
    __syncthreads();
    *(bf16x8*)&sQ[0][crow][ccol] = a0;
    *(bf16x8*)&sQ[1][crow][ccol] = a1;
    *(bf16x8*)&sQ[2][crow][ccol] = a2;
    *(bf16x8*)&sQ[3][crow][ccol] = a3;
    *(bf16x8*)&sK[0][crow][ccol] = b0;
    *(bf16x8*)&sK[1][crow][ccol] = b1;
    *(bf16x8*)&sK[2][crow][ccol] = b2;
    *(bf16x8*)&sK[3][crow][ccol] = b3;
    __syncthreads();
    const int fr = lane & 15, kc = (lane >> 4) * 8;
    bf16x8 fqh[2], fql[2], fq2[2], fqv[2];
#pragma unroll
    for (int i = 0; i < 2; ++i) {
      int r = wm * 32 + i * 16 + fr;
      fqh[i] = *(const bf16x8*)&sQ[0][r][kc];
      fql[i] = *(const bf16x8*)&sQ[1][r][kc];
      fq2[i] = *(const bf16x8*)&sQ[2][r][kc];
      fqv[i] = *(const bf16x8*)&sQ[3][r][kc];
    }
#pragma unroll
    for (int j = 0; j < 2; ++j) {
      int r = wn * 32 + j * 16 + fr;
      bf16x8 fkh = *(const bf16x8*)&sK[0][r][kc];
      bf16x8 fkl = *(const bf16x8*)&sK[1][r][kc];
      bf16x8 fk2 = *(const bf16x8*)&sK[2][r][kc];
      bf16x8 fkv = *(const bf16x8*)&sK[3][r][kc];
#pragma unroll
      for (int i = 0; i < 2; ++i) {
        accM[i][j] = mfma16(fqh[i], fkh, accM[i][j]);
        accM[i][j] = mfma16(fqh[i], fkl, accM[i][j]);
        accM[i][j] = mfma16(fql[i], fkh, accM[i][j]);
        accV[i][j] = mfma16(fq2[i], fkv, accV[i][j]);
        accV[i][j] = mfma16(fqv[i], fk2, accV[i][j]);
        accV[i][j] = mfma16(fqv[i], fkv, accV[i][j]);
      }
    }
  }
  const float itau = 1.0f / *taup;
  const int fr = lane & 15, fq = lane >> 4;
#pragma unroll
  for (int i = 0; i < 2; ++i)
#pragma unroll
    for (int j = 0; j < 2; ++j) {
      const int col = kk0 + wn * 32 + j * 16 + fr;
      const int row0 = q0 + wm * 32 + i * 16 + fq * 4;
      f32x4 m_ = accM[i][j], v_ = accV[i][j];
#pragma unroll
      for (int r = 0; r < 4; ++r) {
        size_t off = ((size_t)bh * S_ + row0 + r) * S_ + col;
        lmu[off] = m_[r] * 0.125f * itau;
        float lv = ((v_[r] + 1e-6f) * (1.0f / 64.0f) + 1e-6f) * itau * itau + 1e-6f;
        lvar[off] = (__bf16)lv;
      }
    }
}

// ---------- attention combine: top-8, MC softmax, rest softmax ----------
__global__ __launch_bounds__(256) void attn_kernel(
    const float* __restrict__ lmu, const __bf16* __restrict__ lvar,
    const float* __restrict__ eps, __bf16* __restrict__ ah, __bf16* __restrict__ al)
{
  const int wid = threadIdx.x >> 6;
  const int lane = threadIdx.x & 63;
  const size_t r = (size_t)blockIdx.x * 4 + wid;
  const float* mrow = lmu + r * S_;
  const __bf16* vrow = lvar + r * S_;
  float mu[8], va[8], sd[8];
#pragma unroll
  for (int i = 0; i < 8; ++i) {
    mu[i] = mrow[lane + 64 * i];
    va[i] = (float)vrow[lane + 64 * i];
    sd[i] = sqrtf(fmaxf(va[i], 1e-9f));
  }
  unsigned sel = 0;
  float x[8];
#pragma unroll
  for (int i = 0; i < 8; ++i) x[i] = mu[i];
  for (int tsel = 0; tsel < 8; ++tsel) {
    float bv = -INFINITY; int bi = 0x7fffffff;
#pragma unroll
    for (int i = 0; i < 8; ++i) {
      int gi = lane + 64 * i;
      if (x[i] > bv || (x[i] == bv && gi < bi)) { bv = x[i]; bi = gi; }
    }
    for (int o = 32; o; o >>= 1) {
      float ov = __shfl_xor(bv, o); int oi = __shfl_xor(bi, o);
      if (ov > bv || (ov == bv && oi < bi)) { bv = ov; bi = oi; }
    }
    if ((bi & 63) == lane) { sel |= 1u << (bi >> 6); x[bi >> 6] = -INFINITY; }
  }
  float pacc[8] = {0, 0, 0, 0, 0, 0, 0, 0};
  for (int mc = 0; mc < MCK; ++mc) {
    const float* ep = eps + (size_t)mc * BHSS_ + r * S_ + lane;
    float xv[8];
#pragma unroll
    for (int i = 0; i < 8; ++i) xv[i] = mu[i] + sd[i] * ep[64 * i];
    float m = -INFINITY;
#pragma unroll
    for (int i = 0; i < 8; ++i) m = fmaxf(m, xv[i]);
    m = wave_max(m);
    float e[8], zs = 0.f;
#pragma unroll
    for (int i = 0; i < 8; ++i) { e[i] = __expf(xv[i] - m); zs += e[i]; }
    zs = wave_sum(zs);
    float inv = 1.0f / zs;
#pragma unroll
    for (int i = 0; i < 8; ++i) pacc[i] += e[i] * inv;
  }
  float adj[8];
#pragma unroll
  for (int i = 0; i < 8; ++i) {
    float a = mu[i] / sqrtf(1.0f + 0.39269908169872414f * va[i]);
    adj[i] = ((sel >> i) & 1u) ? -1e9f : a;
  }
  float m2 = -INFINITY;
#pragma unroll
  for (int i = 0; i < 8; ++i) m2 = fmaxf(m2, adj[i]);
  m2 = wave_max(m2);
  float e2[8], z2 = 0.f;
#pragma unroll
  for (int i = 0; i < 8; ++i) { e2[i] = __expf(adj[i] - m2); z2 += e2[i]; }
  z2 = wave_sum(z2);
  float inv2 = 1.0f / z2;
  float rest[8], tout[8], s = 0.f;
#pragma unroll
  for (int i = 0; i < 8; ++i) {
    rest[i] = e2[i] * inv2;
    tout[i] = ((sel >> i) & 1u) ? pacc[i] * 0.125f : rest[i];
    s += tout[i];
  }
  s = wave_sum(s);
  float rn = 1.0f / fmaxf(s, 1e-12f);
#pragma unroll
  for (int i = 0; i < 8; ++i) {
    float o = tout[i] * rn + rest[i];
    __bf16 h = (__bf16)o;
    ah[r * S_ + lane + 64 * i] = h;
    al[r * S_ + lane + 64 * i] = (__bf16)(o - (float)h);
  }
}

// ---------- PV: Y_mu = attn@vm (split), Y_var = attn^2@vv; write y hi/lo/sc2 ----------
__global__ __launch_bounds__(256) void pv_mfma(
    const __bf16* __restrict__ ah_, const __bf16* __restrict__ al_,
    const __bf16* __restrict__ vTh, const __bf16* __restrict__ vTl,
    const __bf16* __restrict__ vTv,
    __bf16* __restrict__ yh, __bf16* __restrict__ yl, __bf16* __restrict__ ys2)
{
  __shared__ __bf16 sA[2][64][32];
  __shared__ __bf16 sV[3][64][32];
  const int t = threadIdx.x;
  const int lane = t & 63, wid = t >> 6;
  const int wm = wid >> 1, wn = wid & 1;
  const int q0 = blockIdx.x * 64, bh = blockIdx.y;
  const int b = bh >> 4, h = bh & 15;
  const __bf16* Ah = ah_ + (size_t)bh * S_ * S_;
  const __bf16* Al = al_ + (size_t)bh * S_ * S_;
  const __bf16* Vh = vTh + (size_t)bh * 64 * S_;
  const __bf16* Vl = vTl + (size_t)bh * 64 * S_;
  const __bf16* Vv = vTv + (size_t)bh * 64 * S_;
  f32x4 accM[2][2] = {}; f32x4 accV[2][2] = {};
  const int crow = t >> 2, ccol = (t & 3) * 8;
  for (int k0 = 0; k0 < S_; k0 += 32) {
    size_t gA = (size_t)(q0 + crow) * S_ + k0 + ccol;
    size_t gV = (size_t)crow * S_ + k0 + ccol;
    bf16x8 a0 = *(const bf16x8*)(Ah + gA);
    bf16x8 a1 = *(const bf16x8*)(Al + gA);
    bf16x8 v0 = *(const bf16x8*)(Vh + gV);
    bf16x8 v1 = *(const bf16x8*)(Vl + gV);
    bf16x8 v2 = *(const bf16x8*)(Vv + gV);
    __syncthreads();
    *(bf16x8*)&sA[0][crow][ccol] = a0;
    *(bf16x8*)&sA[1][crow][ccol] = a1;
    *(bf16x8*)&sV[0][crow][ccol] = v0;
    *(bf16x8*)&sV[1][crow][ccol] = v1;
    *(bf16x8*)&sV[2][crow][ccol] = v2;
    __syncthreads();
    const int fr = lane & 15, kc = (lane >> 4) * 8;
    bf16x8 fah[2], fal[2], fa2[2];
#pragma unroll
    for (int i = 0; i < 2; ++i) {
      int rr = wm * 32 + i * 16 + fr;
      fah[i] = *(const bf16x8*)&sA[0][rr][kc];
      fal[i] = *(const bf16x8*)&sA[1][rr][kc];
      fa2[i] = sq8(fah[i]);
    }
#pragma unroll
    for (int j = 0; j < 2; ++j) {
      int rr = wn * 32 + j * 16 + fr;
      bf16x8 fvh = *(const bf16x8*)&sV[0][rr][kc];
      bf16x8 fvl = *(const bf16x8*)&sV[1][rr][kc];
      bf16x8 fvv = *(const bf16x8*)&sV[2][rr][kc];
#pragma unroll
      for (int i = 0; i < 2; ++i) {
        accM[i][j] = mfma16(fah[i], fvh, accM[i][j]);
        accM[i][j] = mfma16(fah[i], fvl, accM[i][j]);
        accM[i][j] = mfma16(fal[i], fvh, accM[i][j]);
        accV[i][j] = mfma16(fa2[i], fvv, accV[i][j]);
      }
    }
  }
  const int fr = lane & 15, fq = lane >> 4;
#pragma unroll
  for (int i = 0; i < 2; ++i)
#pragma unroll
    for (int j = 0; j < 2; ++j) {
      const int col = h * 64 + wn * 32 + j * 16 + fr;
      const int row0 = b * S_ + q0 + wm * 32 + i * 16 + fq * 4;
      f32x4 m_ = accM[i][j], v_ = accV[i][j];
#pragma unroll
      for (int r = 0; r < 4; ++r) {
        size_t off = (size_t)(row0 + r) * D_ + col;
        float mu = m_[r];
        __bf16 hh = (__bf16)mu;
        float ss = sqrtf(v_[r] + 1e-6f) + 1e-6f;
        yh[off] = hh;
        yl[off] = (__bf16)(mu - (float)hh);
        ys2[off] = (__bf16)(ss * ss);
      }
    }
}

extern "C" void kernel_launch(void* const* d_in, const int* in_sizes, int n_in,
                              void* d_out, int out_size, void* d_ws, size_t ws_size,
                              hipStream_t stream)
{
  const float* Qloc = (const float*)d_in[0];
  const float* Qsc  = (const float*)d_in[1];
  const float* Kloc = (const float*)d_in[2];
  const float* Ksc  = (const float*)d_in[3];
  const float* Vloc = (const float*)d_in[4];
  const float* Vsc  = (const float*)d_in[5];
  const float* Wq = (const float*)d_in[6];  const float* bq = (const float*)d_in[7];
  const float* Wk = (const float*)d_in[8];  const float* bk = (const float*)d_in[9];
  const float* Wv = (const float*)d_in[10]; const float* bv = (const float*)d_in[11];
  const float* Wo = (const float*)d_in[12]; const float* bo = (const float*)d_in[13];
  const float* tau = (const float*)d_in[14];
  const float* eps = (const float*)d_in[15];

  const size_t P = (size_t)MS * D_;     // 2M elements
  const size_t DD = (size_t)D_ * D_;    // 1M elements
  char* w = (char*)d_ws;
  auto carve = [&](size_t bytes) -> char* {
    char* p = w; w += (bytes + 255) & ~(size_t)255; return p;
  };
  __bf16* cQh = (__bf16*)carve(P * 2); __bf16* cQl = (__bf16*)carve(P * 2); __bf16* cQ2 = (__bf16*)carve(P * 2);
  __bf16* cKh = (__bf16*)carve(P * 2); __bf16* cKl = (__bf16*)carve(P * 2); __bf16* cK2 = (__bf16*)carve(P * 2);
  __bf16* cVh = (__bf16*)carve(P * 2); __bf16* cVl = (__bf16*)carve(P * 2); __bf16* cV2 = (__bf16*)carve(P * 2);
  __bf16* wqh = (__bf16*)carve(DD * 2); __bf16* wql = (__bf16*)carve(DD * 2); __bf16* wq2 = (__bf16*)carve(DD * 2);
  __bf16* wkh = (__bf16*)carve(DD * 2); __bf16* wkl = (__bf16*)carve(DD * 2); __bf16* wk2 = (__bf16*)carve(DD * 2);
  __bf16* wvh = (__bf16*)carve(DD * 2); __bf16* wvl = (__bf16*)carve(DD * 2); __bf16* wv2 = (__bf16*)carve(DD * 2);
  __bf16* woh = (__bf16*)carve(DD * 2); __bf16* wol = (__bf16*)carve(DD * 2); __bf16* wo2 = (__bf16*)carve(DD * 2);
  __bf16* qmh = (__bf16*)carve(P * 2); __bf16* qml = (__bf16*)carve(P * 2);
  __bf16* qm2 = (__bf16*)carve(P * 2); __bf16* qmv = (__bf16*)carve(P * 2);
  __bf16* kmh = (__bf16*)carve(P * 2); __bf16* kml = (__bf16*)carve(P * 2);
  __bf16* km2 = (__bf16*)carve(P * 2); __bf16* kmv = (__bf16*)carve(P * 2);
  __bf16* vTh = (__bf16*)carve(P * 2); __bf16* vTl = (__bf16*)carve(P * 2); __bf16* vTv = (__bf16*)carve(P * 2);
  float*  lmu = (float*)carve(BHSS_ * 4);
  __bf16* lvr = (__bf16*)carve(BHSS_ * 2);
  __bf16* ath = (__bf16*)carve(BHSS_ * 2);
  __bf16* atl = (__bf16*)carve(BHSS_ * 2);
  __bf16* yh = (__bf16*)carve(P * 2); __bf16* yl = (__bf16*)carve(P * 2); __bf16* ys2 = (__bf16*)carve(P * 2);
  float* out_loc = (float*)d_out;
  float* out_sc  = out_loc + P;

  dim3 blk(256);
  conv_ls<<<3 * 1024, blk, 0, stream>>>(Qloc, Qsc, Kloc, Ksc, Vloc, Vsc,
                                        cQh, cQl, cQ2, cKh, cKl, cK2, cVh, cVl, cV2);
  conv_w<<<4 * 512, blk, 0, stream>>>(Wq, Wk, Wv, Wo,
                                      wqh, wql, wq2, wkh, wkl, wk2,
                                      wvh, wvl, wv2, woh, wol, wo2);
  dim3 gG(16, 32);
  dgemm<0><<<gG, blk, 0, stream>>>(cQh, cQl, cQ2, wqh, wql, wq2, bq, qmh, qml, qm2, qmv);
  dgemm<0><<<gG, blk, 0, stream>>>(cKh, cKl, cK2, wkh, wkl, wk2, bk, kmh, kml, km2, kmv);
  dgemm<1><<<gG, blk, 0, stream>>>(cVh, cVl, cV2, wvh, wvl, wv2, bv, vTh, vTl, vTv, nullptr);
  score_mfma<<<dim3(8, 8, 64), blk, 0, stream>>>(qmh, qml, qm2, qmv, kmh, kml, km2, kmv, lmu, lvr, tau);
  attn_kernel<<<dim3((unsigned)(BHS_ / 4)), blk, 0, stream>>>(lmu, lvr, eps, ath, atl);
  pv_mfma<<<dim3(8, 64), blk, 0, stream>>>(ath, atl, vTh, vTl, vTv, yh, yl, ys2);
  dgemm<2><<<gG, blk, 0, stream>>>(yh, yl, ys2, woh, wol, wo2, bo, out_loc, out_sc, nullptr, nullptr);
}

// Round 3
// 390.260 us; speedup vs baseline: 2.1866x; 1.0340x over previous
//
#include <hip/hip_runtime.h>
#include <math.h>

#define B_ 4
#define S_ 512
#define D_ 1024
#define H_ 16
#define MCK 8
#define MS 2048
#define BHSS_ ((size_t)16777216)   // B*H*S*S
#define BHS_  ((size_t)32768)

typedef __attribute__((ext_vector_type(8))) __bf16 bf16x8;
typedef __attribute__((ext_vector_type(4))) __bf16 bf16x4;
typedef __attribute__((ext_vector_type(4))) float f32x4;

__device__ __forceinline__ f32x4 mfma16(bf16x8 a, bf16x8 b, f32x4 c) {
  return __builtin_amdgcn_mfma_f32_16x16x32_bf16(a, b, c, 0, 0, 0);
}
__device__ __forceinline__ bf16x8 sq8(bf16x8 x) {
  bf16x8 r;
#pragma unroll
  for (int i = 0; i < 8; ++i) { float f = (float)x[i]; r[i] = (__bf16)(f * f); }
  return r;
}
// (Wh+Wl)^2 elementwise -> bf16
__device__ __forceinline__ bf16x8 sq8s(bf16x8 h, bf16x8 l) {
  bf16x8 r;
#pragma unroll
  for (int i = 0; i < 8; ++i) { float f = (float)h[i] + (float)l[i]; r[i] = (__bf16)(f * f); }
  return r;
}
__device__ __forceinline__ float wave_max(float v) {
#pragma unroll
  for (int o = 32; o; o >>= 1) v = fmaxf(v, __shfl_xor(v, o));
  return v;
}
__device__ __forceinline__ float wave_sum(float v) {
#pragma unroll
  for (int o = 32; o; o >>= 1) v += __shfl_xor(v, o);
  return v;
}

// ---- LDS swizzle: 16B slot address for logical (row, slot) is (row*4+slot)^(row&7).
// inverse: given linear slot u, which (row,slot) must be fetched from global so the
// swizzled read finds it.
__device__ __forceinline__ void unswz(int u, int& row, int& slot) {
  int row0 = ((u >> 2) ^ (u >> 4)) & 1;
  row = ((u >> 3) << 1) | row0;
  int s0 = (u ^ (u >> 2) ^ (u >> 4)) & 1;
  int s1 = ((u >> 1) ^ (u >> 3)) & 1;
  slot = (s1 << 1) | s0;
}
__device__ __forceinline__ int swz_el(int row, int slot) {   // element offset in [rows][32] tile
  return ((row * 4 + slot) ^ (row & 7)) * 8;
}
__device__ __forceinline__ void glds16(const void* gsrc, void* ldst) {
  __builtin_amdgcn_global_load_lds(
      (const __attribute__((address_space(1))) void*)gsrc,
      (__attribute__((address_space(3))) void*)ldst, 16, 0, 0);
}

// ---------- input conversion: (loc,scale) -> (hi, lo, scale^2) bf16 ----------
__global__ __launch_bounds__(256) void conv_ls(
    const float* __restrict__ l0, const float* __restrict__ s0,
    const float* __restrict__ l1, const float* __restrict__ s1,
    const float* __restrict__ l2, const float* __restrict__ s2,
    __bf16* h0, __bf16* o0, __bf16* v0,
    __bf16* h1, __bf16* o1, __bf16* v1,
    __bf16* h2, __bf16* o2, __bf16* v2)
{
  const int tn = blockIdx.x >> 10;
  const size_t i0 = ((size_t)(blockIdx.x & 1023) * 256 + threadIdx.x) * 8;
  const float* L = tn == 0 ? l0 : tn == 1 ? l1 : l2;
  const float* S = tn == 0 ? s0 : tn == 1 ? s1 : s2;
  __bf16* Hh = tn == 0 ? h0 : tn == 1 ? h1 : h2;
  __bf16* Lo = tn == 0 ? o0 : tn == 1 ? o1 : o2;
  __bf16* V2 = tn == 0 ? v0 : tn == 1 ? v1 : v2;
  float4 x0 = *(const float4*)(L + i0), x1 = *(const float4*)(L + i0 + 4);
  float4 y0 = *(const float4*)(S + i0), y1 = *(const float4*)(S + i0 + 4);
  float xs[8] = {x0.x, x0.y, x0.z, x0.w, x1.x, x1.y, x1.z, x1.w};
  float ys[8] = {y0.x, y0.y, y0.z, y0.w, y1.x, y1.y, y1.z, y1.w};
  bf16x8 hh, ll, vv;
#pragma unroll
  for (int i = 0; i < 8; ++i) {
    __bf16 h = (__bf16)xs[i];
    hh[i] = h;
    ll[i] = (__bf16)(xs[i] - (float)h);
    vv[i] = (__bf16)(ys[i] * ys[i]);
  }
  *(bf16x8*)(Hh + i0) = hh;
  *(bf16x8*)(Lo + i0) = ll;
  *(bf16x8*)(V2 + i0) = vv;
}

// ---------- weight conversion: W -> (hi, lo) bf16 ----------
__global__ __launch_bounds__(256) void conv_w(
    const float* __restrict__ w0, const float* __restrict__ w1,
    const float* __restrict__ w2, const float* __restrict__ w3,
    __bf16* h0, __bf16* o0, __bf16* h1, __bf16* o1,
    __bf16* h2, __bf16* o2, __bf16* h3, __bf16* o3)
{
  const int tn = blockIdx.x >> 9;
  const size_t i0 = ((size_t)(blockIdx.x & 511) * 256 + threadIdx.x) * 8;
  const float* W = tn == 0 ? w0 : tn == 1 ? w1 : tn == 2 ? w2 : w3;
  __bf16* Hh = tn == 0 ? h0 : tn == 1 ? h1 : tn == 2 ? h2 : h3;
  __bf16* Lo = tn == 0 ? o0 : tn == 1 ? o1 : tn == 2 ? o2 : o3;
  float4 x0 = *(const float4*)(W + i0), x1 = *(const float4*)(W + i0 + 4);
  float xs[8] = {x0.x, x0.y, x0.z, x0.w, x1.x, x1.y, x1.z, x1.w};
  bf16x8 hh, ll;
#pragma unroll
  for (int i = 0; i < 8; ++i) {
    __bf16 h = (__bf16)xs[i];
    hh[i] = h;
    ll[i] = (__bf16)(xs[i] - (float)h);
  }
  *(bf16x8*)(Hh + i0) = hh;
  *(bf16x8*)(Lo + i0) = ll;
}

// ---------- batched dual-GEMM projection (64x128 block, 4 waves, glds+swizzle) ----
// mu = (Ah+Al)@(Wh+Wl)^T + bias (3 MFMA), var = A2 @ ((Wh+Wl)^2)^T (1 MFMA, W2 in-reg)
// epi 0 (Q/K): write mu_hi, mu_lo, mu^2, (sqrt(var)+1e-6)^2     [2048][1024] bf16
// epi 1 (V):   write transposed vT_hi, vT_lo, vT_var            [B][H][64][512] bf16
struct PArg {
  const __bf16 *Ah, *Al, *A2, *Wh, *Wl;
  const float* bias;
  __bf16 *P0, *P1, *P2, *P3;
  int epi;
};
struct PArg3 { PArg a[3]; };

// LDS element offsets: Ah 0, Al 2048, A2 4096, Wh 6144, Wl 10240  (total 14336 el = 28KB)
__global__ __launch_bounds__(256, 3) void dgemm_qkv(PArg3 P3v)
{
  __shared__ __bf16 lds[14336];
  const PArg p = P3v.a[blockIdx.z];
  const int t = threadIdx.x, lane = t & 63, wid = t >> 6;
  const int m0 = blockIdx.y * 64, n0 = blockIdx.x * 128;
  int rA, sA; unswz(t, rA, sA);
  const size_t gA = (size_t)(m0 + rA) * D_ + sA * 8;
  const size_t gW0 = (size_t)(n0 + rA) * D_ + sA * 8;
  int rW1, sW1; unswz(t + 256, rW1, sW1);
  const size_t gW1 = (size_t)(n0 + rW1) * D_ + sW1 * 8;
  const int wofs = wid * 512;     // wave-uniform LDS element offset (64 lanes * 8 el)
  f32x4 accM[4][2] = {}; f32x4 accV[4][2] = {};
  const int fr = lane & 15, ks = lane >> 4;
  for (int k0 = 0; k0 < D_; k0 += 32) {
    if (k0) __syncthreads();
    glds16(p.Ah + gA + k0,  lds + 0     + wofs);
    glds16(p.Al + gA + k0,  lds + 2048  + wofs);
    glds16(p.A2 + gA + k0,  lds + 4096  + wofs);
    glds16(p.Wh + gW0 + k0, lds + 6144  + wofs);
    glds16(p.Wl + gW0 + k0, lds + 10240 + wofs);
    glds16(p.Wh + gW1 + k0, lds + 6144 + 2048 + wofs);
    glds16(p.Wl + gW1 + k0, lds + 10240 + 2048 + wofs);
    __syncthreads();
    bf16x8 fah[4], fal[4], fa2[4];
#pragma unroll
    for (int i = 0; i < 4; ++i) {
      int so = swz_el(i * 16 + fr, ks);
      fah[i] = *(const bf16x8*)(lds + 0 + so);
      fal[i] = *(const bf16x8*)(lds + 2048 + so);
      fa2[i] = *(const bf16x8*)(lds + 4096 + so);
    }
#pragma unroll
    for (int j = 0; j < 2; ++j) {
      int so = swz_el(wid * 32 + j * 16 + fr, ks);
      bf16x8 fwh = *(const bf16x8*)(lds + 6144 + so);
      bf16x8 fwl = *(const bf16x8*)(lds + 10240 + so);
      bf16x8 fw2 = sq8s(fwh, fwl);
#pragma unroll
      for (int i = 0; i < 4; ++i) {
        accM[i][j] = mfma16(fah[i], fwh, accM[i][j]);
        accM[i][j] = mfma16(fah[i], fwl, accM[i][j]);
        accM[i][j] = mfma16(fal[i], fwh, accM[i][j]);
        accV[i][j] = mfma16(fa2[i], fw2, accV[i][j]);
      }
    }
  }
  const int fq = lane >> 4;
#pragma unroll
  for (int j = 0; j < 2; ++j) {
    const int col = n0 + wid * 32 + j * 16 + fr;
    const float bcol = p.bias[col];
#pragma unroll
    for (int i = 0; i < 4; ++i) {
      const int row0 = m0 + i * 16 + fq * 4;
      f32x4 m_ = accM[i][j], v_ = accV[i][j];
      if (p.epi == 0) {
#pragma unroll
        for (int r = 0; r < 4; ++r) {
          size_t off = (size_t)(row0 + r) * D_ + col;
          float mu = m_[r] + bcol;
          __bf16 h = (__bf16)mu;
          float s = sqrtf(v_[r]) + 1e-6f;
          p.P0[off] = h;
          p.P1[off] = (__bf16)(mu - (float)h);
          p.P2[off] = (__bf16)(mu * mu);
          p.P3[off] = (__bf16)(s * s);
        }
      } else {
        const int b = row0 >> 9, ss0 = row0 & 511;
        const int hh = col >> 6, dd = col & 63;
        size_t base = ((size_t)(b * H_ + hh) * 64 + dd) * S_ + ss0;
        bf16x4 vh, vl, vq;
#pragma unroll
        for (int r = 0; r < 4; ++r) {
          float mu = m_[r] + bcol;
          __bf16 h = (__bf16)mu;
          vh[r] = h;
          vl[r] = (__bf16)(mu - (float)h);
          float s = sqrtf(v_[r]) + 1e-6f;
          vq[r] = (__bf16)(s * s);
        }
        *(bf16x4*)(p.P0 + base) = vh;
        *(bf16x4*)(p.P1 + base) = vl;
        *(bf16x4*)(p.P2 + base) = vq;
      }
    }
  }
}

// ---------- output projection: same structure, f32 epilogue ----------
__global__ __launch_bounds__(256) void dgemm_o(
    const __bf16* __restrict__ Ah, const __bf16* __restrict__ Al, const __bf16* __restrict__ A2,
    const __bf16* __restrict__ Wh, const __bf16* __restrict__ Wl,
    const float* __restrict__ bias, float* __restrict__ O0, float* __restrict__ O1)
{
  __shared__ __bf16 lds[14336];
  const int t = threadIdx.x, lane = t & 63, wid = t >> 6;
  const int m0 = blockIdx.y * 64, n0 = blockIdx.x * 128;
  int rA, sA; unswz(t, rA, sA);
  const size_t gA = (size_t)(m0 + rA) * D_ + sA * 8;
  const size_t gW0 = (size_t)(n0 + rA) * D_ + sA * 8;
  int rW1, sW1; unswz(t + 256, rW1, sW1);
  const size_t gW1 = (size_t)(n0 + rW1) * D_ + sW1 * 8;
  const int wofs = wid * 512;
  f32x4 accM[4][2] = {}; f32x4 accV[4][2] = {};
  const int fr = lane & 15, ks = lane >> 4;
  for (int k0 = 0; k0 < D_; k0 += 32) {
    if (k0) __syncthreads();
    glds16(Ah + gA + k0,  lds + 0     + wofs);
    glds16(Al + gA + k0,  lds + 2048  + wofs);
    glds16(A2 + gA + k0,  lds + 4096  + wofs);
    glds16(Wh + gW0 + k0, lds + 6144  + wofs);
    glds16(Wl + gW0 + k0, lds + 10240 + wofs);
    glds16(Wh + gW1 + k0, lds + 6144 + 2048 + wofs);
    glds16(Wl + gW1 + k0, lds + 10240 + 2048 + wofs);
    __syncthreads();
    bf16x8 fah[4], fal[4], fa2[4];
#pragma unroll
    for (int i = 0; i < 4; ++i) {
      int so = swz_el(i * 16 + fr, ks);
      fah[i] = *(const bf16x8*)(lds + 0 + so);
      fal[i] = *(const bf16x8*)(lds + 2048 + so);
      fa2[i] = *(const bf16x8*)(lds + 4096 + so);
    }
#pragma unroll
    for (int j = 0; j < 2; ++j) {
      int so = swz_el(wid * 32 + j * 16 + fr, ks);
      bf16x8 fwh = *(const bf16x8*)(lds + 6144 + so);
      bf16x8 fwl = *(const bf16x8*)(lds + 10240 + so);
      bf16x8 fw2 = sq8s(fwh, fwl);
#pragma unroll
      for (int i = 0; i < 4; ++i) {
        accM[i][j] = mfma16(fah[i], fwh, accM[i][j]);
        accM[i][j] = mfma16(fah[i], fwl, accM[i][j]);
        accM[i][j] = mfma16(fal[i], fwh, accM[i][j]);
        accV[i][j] = mfma16(fa2[i], fw2, accV[i][j]);
      }
    }
  }
  const int fq = lane >> 4;
#pragma unroll
  for (int j = 0; j < 2; ++j) {
    const int col = n0 + wid * 32 + j * 16 + fr;
    const float bcol = bias[col];
#pragma unroll
    for (int i = 0; i < 4; ++i) {
      const int row0 = m0 + i * 16 + fq * 4;
      f32x4 m_ = accM[i][j], v_ = accV[i][j];
#pragma unroll
      for (int r = 0; r < 4; ++r) {
        size_t off = (size_t)(row0 + r) * D_ + col;
        O0[off] = m_[r] + bcol;
        O1[off] = sqrtf(v_[r]);
      }
    }
  }
}

// ---------- score: l_mu (f32, split-precision) and l_var (bf16) ----------
__global__ __launch_bounds__(256) void score_mfma(
    const __bf16* __restrict__ qh, const __bf16* __restrict__ ql,
    const __bf16* __restrict__ q2, const __bf16* __restrict__ qv,
    const __bf16* __restrict__ kh, const __bf16* __restrict__ kl,
    const __bf16* __restrict__ k2, const __bf16* __restrict__ kv,
    float* __restrict__ lmu, __bf16* __restrict__ lvar,
    const float* __restrict__ taup)
{
  __shared__ __bf16 sQ[4][64][32];
  __shared__ __bf16 sK[4][64][32];
  const int t = threadIdx.x;
  const int lane = t & 63, wid = t >> 6;
  const int wm = wid >> 1, wn = wid & 1;
  const int kk0 = blockIdx.x * 64, q0 = blockIdx.y * 64, bh = blockIdx.z;
  const int b = bh >> 4, h = bh & 15;
  const size_t hb = ((size_t)b * S_) * D_ + (size_t)h * 64;
  f32x4 accM[2][2] = {}; f32x4 accV[2][2] = {};
  const int crow = t >> 2, ccol = (t & 3) * 8;
  for (int d0 = 0; d0 < 64; d0 += 32) {
    size_t gq = hb + (size_t)(q0 + crow) * D_ + d0 + ccol;
    size_t gk = hb + (size_t)(kk0 + crow) * D_ + d0 + ccol;
    bf16x8 a0 = *(const bf16x8*)(qh + gq);
    bf16x8 a1 = *(const bf16x8*)(ql + gq);
    bf16x8 a2 = *(const bf16x8*)(q2 + gq);
    bf16x8 a3 = *(const bf16x8*)(qv + gq);
    bf16x8 b0 = *(const bf16x8*)(kh + gk);
    bf16x8 b1 = *(const bf16x8*)(kl + gk);
    bf16x8 b2 = *(const bf16x8*)(k2 + gk);
    bf16x8 b3 = *(const bf16x8*)(kv + gk);
    __syncthreads();
    *(bf16x8*)&sQ[0][crow][ccol] = a0;
    *(bf16x8*)&sQ[1][crow][ccol] = a1;
    *(bf16x8*)&sQ[2][crow][ccol] = a2;
    *(bf16x8*)&sQ[3][crow][ccol] = a3;
    *(bf16x8*)&sK[0][crow][ccol] = b0;
    *(bf16x8*)&sK[1][crow][ccol] = b1;
    *(bf16x8*)&sK[2][crow][ccol] = b2;
    *(bf16x8*)&sK[3][crow][ccol] = b3;
    __syncthreads();
    const int fr = lane & 15, kc = (lane >> 4) * 8;
    bf16x8 fqh[2], fql[2], fq2[2], fqv[2];
#pragma unroll
    for (int i = 0; i < 2; ++i) {
      int r = wm * 32 + i * 16 + fr;
      fqh[i] = *(const bf16x8*)&sQ[0][r][kc];
      fql[i] = *(const bf16x8*)&sQ[1][r][kc];
      fq2[i] = *(const bf16x8*)&sQ[2][r][kc];
      fqv[i] = *(const bf16x8*)&sQ[3][r][kc];
    }
#pragma unroll
    for (int j = 0; j < 2; ++j) {
      int r = wn * 32 + j * 16 + fr;
      bf16x8 fkh = *(const bf16x8*)&sK[0][r][kc];
      bf16x8 fkl = *(const bf16x8*)&sK[1][r][kc];
      bf16x8 fk2 = *(const bf16x8*)&sK[2][r][kc];
      bf16x8 fkv = *(const bf16x8*)&sK[3][r][kc];
#pragma unroll
      for (int i = 0; i < 2; ++i) {
        accM[i][j] = mfma16(fqh[i], fkh, accM[i][j]);
        accM[i][j] = mfma16(fqh[i], fkl, accM[i][j]);
        accM[i][j] = mfma16(fql[i], fkh, accM[i][j]);
        accV[i][j] = mfma16(fq2[i], fkv, accV[i][j]);
        accV[i][j] = mfma16(fqv[i], fk2, accV[i][j]);
        accV[i][j] = mfma16(fqv[i], fkv, accV[i][j]);
      }
    }
  }
  const float itau = 1.0f / *taup;
  const int fr = lane & 15, fq = lane >> 4;
#pragma unroll
  for (int i = 0; i < 2; ++i)
#pragma unroll
    for (int j = 0; j < 2; ++j) {
      const int col = kk0 + wn * 32 + j * 16 + fr;
      const int row0 = q0 + wm * 32 + i * 16 + fq * 4;
      f32x4 m_ = accM[i][j], v_ = accV[i][j];
#pragma unroll
      for (int r = 0; r < 4; ++r) {
        size_t off = ((size_t)bh * S_ + row0 + r) * S_ + col;
        lmu[off] = m_[r] * 0.125f * itau;
        float lv = ((v_[r] + 1e-6f) * (1.0f / 64.0f) + 1e-6f) * itau * itau + 1e-6f;
        lvar[off] = (__bf16)lv;
      }
    }
}

// ---------- attention combine: top-8, MC softmax, rest softmax ----------
__global__ __launch_bounds__(256) void attn_kernel(
    const float* __restrict__ lmu, const __bf16* __restrict__ lvar,
    const float* __restrict__ eps, __bf16* __restrict__ ah, __bf16* __restrict__ al)
{
  const int wid = threadIdx.x >> 6;
  const int lane = threadIdx.x & 63;
  const size_t r = (size_t)blockIdx.x * 4 + wid;
  const float* mrow = lmu + r * S_;
  const __bf16* vrow = lvar + r * S_;
  float mu[8], va[8], sd[8];
#pragma unroll
  for (int i = 0; i < 8; ++i) {
    mu[i] = mrow[lane + 64 * i];
    va[i] = (float)vrow[lane + 64 * i];
    sd[i] = sqrtf(fmaxf(va[i], 1e-9f));
  }
  unsigned sel = 0;
  float x[8];
#pragma unroll
  for (int i = 0; i < 8; ++i) x[i] = mu[i];
  for (int tsel = 0; tsel < 8; ++tsel) {
    float bv = -INFINITY; int bi = 0x7fffffff;
#pragma unroll
    for (int i = 0; i < 8; ++i) {
      int gi = lane + 64 * i;
      if (x[i] > bv || (x[i] == bv && gi < bi)) { bv = x[i]; bi = gi; }
    }
    for (int o = 32; o; o >>= 1) {
      float ov = __shfl_xor(bv, o); int oi = __shfl_xor(bi, o);
      if (ov > bv || (ov == bv && oi < bi)) { bv = ov; bi = oi; }
    }
    if ((bi & 63) == lane) { sel |= 1u << (bi >> 6); x[bi >> 6] = -INFINITY; }
  }
  float pacc[8] = {0, 0, 0, 0, 0, 0, 0, 0};
  for (int mc = 0; mc < MCK; ++mc) {
    const float* ep = eps + (size_t)mc * BHSS_ + r * S_ + lane;
    float xv[8];
#pragma unroll
    for (int i = 0; i < 8; ++i) xv[i] = mu[i] + sd[i] * ep[64 * i];
    float m = -INFINITY;
#pragma unroll
    for (int i = 0; i < 8; ++i) m = fmaxf(m, xv[i]);
    m = wave_max(m);
    float e[8], zs = 0.f;
#pragma unroll
    for (int i = 0; i < 8; ++i) { e[i] = __expf(xv[i] - m); zs += e[i]; }
    zs = wave_sum(zs);
    float inv = 1.0f / zs;
#pragma unroll
    for (int i = 0; i < 8; ++i) pacc[i] += e[i] * inv;
  }
  float adj[8];
#pragma unroll
  for (int i = 0; i < 8; ++i) {
    float a = mu[i] / sqrtf(1.0f + 0.39269908169872414f * va[i]);
    adj[i] = ((sel >> i) & 1u) ? -1e9f : a;
  }
  float m2 = -INFINITY;
#pragma unroll
  for (int i = 0; i < 8; ++i) m2 = fmaxf(m2, adj[i]);
  m2 = wave_max(m2);
  float e2[8], z2 = 0.f;
#pragma unroll
  for (int i = 0; i < 8; ++i) { e2[i] = __expf(adj[i] - m2); z2 += e2[i]; }
  z2 = wave_sum(z2);
  float inv2 = 1.0f / z2;
  float rest[8], tout[8], s = 0.f;
#pragma unroll
  for (int i = 0; i < 8; ++i) {
    rest[i] = e2[i] * inv2;
    tout[i] = ((sel >> i) & 1u) ? pacc[i] * 0.125f : rest[i];
    s += tout[i];
  }
  s = wave_sum(s);
  float rn = 1.0f / fmaxf(s, 1e-12f);
#pragma unroll
  for (int i = 0; i < 8; ++i) {
    float o = tout[i] * rn + rest[i];
    __bf16 h = (__bf16)o;
    ah[r * S_ + lane + 64 * i] = h;
    al[r * S_ + lane + 64 * i] = (__bf16)(o - (float)h);
  }
}

// ---------- PV: Y_mu = attn@vm (split), Y_var = attn^2@vv; write y hi/lo/sc2 ----------
__global__ __launch_bounds__(256) void pv_mfma(
    const __bf16* __restrict__ ah_, const __bf16* __restrict__ al_,
    const __bf16* __restrict__ vTh, const __bf16* __restrict__ vTl,
    const __bf16* __restrict__ vTv,
    __bf16* __restrict__ yh, __bf16* __restrict__ yl, __bf16* __restrict__ ys2)
{
  __shared__ __bf16 sA[2][64][32];
  __shared__ __bf16 sV[3][64][32];
  const int t = threadIdx.x;
  const int lane = t & 63, wid = t >> 6;
  const int wm = wid >> 1, wn = wid & 1;
  const int q0 = blockIdx.x * 64, bh = blockIdx.y;
  const int b = bh >> 4, h = bh & 15;
  const __bf16* Ah = ah_ + (size_t)bh * S_ * S_;
  const __bf16* Al = al_ + (size_t)bh * S_ * S_;
  const __bf16* Vh = vTh + (size_t)bh * 64 * S_;
  const __bf16* Vl = vTl + (size_t)bh * 64 * S_;
  const __bf16* Vv = vTv + (size_t)bh * 64 * S_;
  f32x4 accM[2][2] = {}; f32x4 accV[2][2] = {};
  const int crow = t >> 2, ccol = (t & 3) * 8;
  for (int k0 = 0; k0 < S_; k0 += 32) {
    size_t gA = (size_t)(q0 + crow) * S_ + k0 + ccol;
    size_t gV = (size_t)crow * S_ + k0 + ccol;
    bf16x8 a0 = *(const bf16x8*)(Ah + gA);
    bf16x8 a1 = *(const bf16x8*)(Al + gA);
    bf16x8 v0 = *(const bf16x8*)(Vh + gV);
    bf16x8 v1 = *(const bf16x8*)(Vl + gV);
    bf16x8 v2 = *(const bf16x8*)(Vv + gV);
    __syncthreads();
    *(bf16x8*)&sA[0][crow][ccol] = a0;
    *(bf16x8*)&sA[1][crow][ccol] = a1;
    *(bf16x8*)&sV[0][crow][ccol] = v0;
    *(bf16x8*)&sV[1][crow][ccol] = v1;
    *(bf16x8*)&sV[2][crow][ccol] = v2;
    __syncthreads();
    const int fr = lane & 15, kc = (lane >> 4) * 8;
    bf16x8 fah[2], fal[2], fa2[2];
#pragma unroll
    for (int i = 0; i < 2; ++i) {
      int rr = wm * 32 + i * 16 + fr;
      fah[i] = *(const bf16x8*)&sA[0][rr][kc];
      fal[i] = *(const bf16x8*)&sA[1][rr][kc];
      fa2[i] = sq8(fah[i]);
    }
#pragma unroll
    for (int j = 0; j < 2; ++j) {
      int rr = wn * 32 + j * 16 + fr;
      bf16x8 fvh = *(const bf16x8*)&sV[0][rr][kc];
      bf16x8 fvl = *(const bf16x8*)&sV[1][rr][kc];
      bf16x8 fvv = *(const bf16x8*)&sV[2][rr][kc];
#pragma unroll
      for (int i = 0; i < 2; ++i) {
        accM[i][j] = mfma16(fah[i], fvh, accM[i][j]);
        accM[i][j] = mfma16(fah[i], fvl, accM[i][j]);
        accM[i][j] = mfma16(fal[i], fvh, accM[i][j]);
        accV[i][j] = mfma16(fa2[i], fvv, accV[i][j]);
      }
    }
  }
  const int fr = lane & 15, fq = lane >> 4;
#pragma unroll
  for (int i = 0; i < 2; ++i)
#pragma unroll
    for (int j = 0; j < 2; ++j) {
      const int col = h * 64 + wn * 32 + j * 16 + fr;
      const int row0 = b * S_ + q0 + wm * 32 + i * 16 + fq * 4;
      f32x4 m_ = accM[i][j], v_ = accV[i][j];
#pragma unroll
      for (int r = 0; r < 4; ++r) {
        size_t off = (size_t)(row0 + r) * D_ + col;
        float mu = m_[r];
        __bf16 hh = (__bf16)mu;
        float ss = sqrtf(v_[r] + 1e-6f) + 1e-6f;
        yh[off] = hh;
        yl[off] = (__bf16)(mu - (float)hh);
        ys2[off] = (__bf16)(ss * ss);
      }
    }
}

extern "C" void kernel_launch(void* const* d_in, const int* in_sizes, int n_in,
                              void* d_out, int out_size, void* d_ws, size_t ws_size,
                              hipStream_t stream)
{
  const float* Qloc = (const float*)d_in[0];
  const float* Qsc  = (const float*)d_in[1];
  const float* Kloc = (const float*)d_in[2];
  const float* Ksc  = (const float*)d_in[3];
  const float* Vloc = (const float*)d_in[4];
  const float* Vsc  = (const float*)d_in[5];
  const float* Wq = (const float*)d_in[6];  const float* bq = (const float*)d_in[7];
  const float* Wk = (const float*)d_in[8];  const float* bk = (const float*)d_in[9];
  const float* Wv = (const float*)d_in[10]; const float* bv = (const float*)d_in[11];
  const float* Wo = (const float*)d_in[12]; const float* bo = (const float*)d_in[13];
  const float* tau = (const float*)d_in[14];
  const float* eps = (const float*)d_in[15];

  const size_t P = (size_t)MS * D_;     // 2M elements
  const size_t DD = (size_t)D_ * D_;    // 1M elements
  char* w = (char*)d_ws;
  auto carve = [&](size_t bytes) -> char* {
    char* p = w; w += (bytes + 255) & ~(size_t)255; return p;
  };
  __bf16* cQh = (__bf16*)carve(P * 2); __bf16* cQl = (__bf16*)carve(P * 2); __bf16* cQ2 = (__bf16*)carve(P * 2);
  __bf16* cKh = (__bf16*)carve(P * 2); __bf16* cKl = (__bf16*)carve(P * 2); __bf16* cK2 = (__bf16*)carve(P * 2);
  __bf16* cVh = (__bf16*)carve(P * 2); __bf16* cVl = (__bf16*)carve(P * 2); __bf16* cV2 = (__bf16*)carve(P * 2);
  __bf16* wqh = (__bf16*)carve(DD * 2); __bf16* wql = (__bf16*)carve(DD * 2);
  __bf16* wkh = (__bf16*)carve(DD * 2); __bf16* wkl = (__bf16*)carve(DD * 2);
  __bf16* wvh = (__bf16*)carve(DD * 2); __bf16* wvl = (__bf16*)carve(DD * 2);
  __bf16* woh = (__bf16*)carve(DD * 2); __bf16* wol = (__bf16*)carve(DD * 2);
  __bf16* qmh = (__bf16*)carve(P * 2); __bf16* qml = (__bf16*)carve(P * 2);
  __bf16* qm2 = (__bf16*)carve(P * 2); __bf16* qmv = (__bf16*)carve(P * 2);
  __bf16* kmh = (__bf16*)carve(P * 2); __bf16* kml = (__bf16*)carve(P * 2);
  __bf16* km2 = (__bf16*)carve(P * 2); __bf16* kmv = (__bf16*)carve(P * 2);
  __bf16* vTh = (__bf16*)carve(P * 2); __bf16* vTl = (__bf16*)carve(P * 2); __bf16* vTv = (__bf16*)carve(P * 2);
  float*  lmu = (float*)carve(BHSS_ * 4);
  __bf16* lvr = (__bf16*)carve(BHSS_ * 2);
  __bf16* ath = (__bf16*)carve(BHSS_ * 2);
  __bf16* atl = (__bf16*)carve(BHSS_ * 2);
  __bf16* yh = (__bf16*)carve(P * 2); __bf16* yl = (__bf16*)carve(P * 2); __bf16* ys2 = (__bf16*)carve(P * 2);
  float* out_loc = (float*)d_out;
  float* out_sc  = out_loc + P;

  dim3 blk(256);
  conv_ls<<<3 * 1024, blk, 0, stream>>>(Qloc, Qsc, Kloc, Ksc, Vloc, Vsc,
                                        cQh, cQl, cQ2, cKh, cKl, cK2, cVh, cVl, cV2);
  conv_w<<<4 * 512, blk, 0, stream>>>(Wq, Wk, Wv, Wo,
                                      wqh, wql, wkh, wkl, wvh, wvl, woh, wol);
  PArg3 pq;
  pq.a[0] = PArg{cQh, cQl, cQ2, wqh, wql, bq, qmh, qml, qm2, qmv, 0};
  pq.a[1] = PArg{cKh, cKl, cK2, wkh, wkl, bk, kmh, kml, km2, kmv, 0};
  pq.a[2] = PArg{cVh, cVl, cV2, wvh, wvl, bv, vTh, vTl, vTv, nullptr, 1};
  dgemm_qkv<<<dim3(8, 32, 3), blk, 0, stream>>>(pq);
  score_mfma<<<dim3(8, 8, 64), blk, 0, stream>>>(qmh, qml, qm2, qmv, kmh, kml, km2, kmv, lmu, lvr, tau);
  attn_kernel<<<dim3((unsigned)(BHS_ / 4)), blk, 0, stream>>>(lmu, lvr, eps, ath, atl);
  pv_mfma<<<dim3(8, 64), blk, 0, stream>>>(ath, atl, vTh, vTl, vTv, yh, yl, ys2);
  dgemm_o<<<dim3(8, 32), blk, 0, stream>>>(yh, yl, ys2, woh, wol, bo, out_loc, out_sc);
}